// Round 16
// baseline (174.526 us; speedup 1.0000x reference)
//
#include <hip/hip_runtime.h>
#include <math.h>
#include <stdint.h>

// Problem constants: B=8192, C=1000, N=2, D=512, return_dists=1
#define NB   8192
#define NCLS 1000
#define NT   2000   // C*N
#define ND   512
#define OUTW 1001

// ---- shared ws scalar layout (float offsets) ----
#define OFF_NORM2C 0        // [2048] centroid row |.|^2 (raw)
#define OFF_R2     2048     // [2048] rejective row |.|^2
#define OFF_X2     4096     // [8192] x row |.|^2
#define OFF_SCAL   12288    // [0]=cnorm [1]=inv [2]=inv^2
#define OFF_IDX    12352    // [8192] int argmin t
#define OFF_CX     20544    // [8192] x.cf[idx]
#define OFF_CL2    28736    // [8192] |cf[idx]|^2

// ---- fast path: u64 argmin keys [8192][32] ----
#define NOFF_MIND  36928    // u64 keys (2 MB)
#define NOFF_REJP  823360   // [8192*32] float

// ---- fallback path (8 segments) ----
#define OFF8_MIND  36928
#define OFF8_MINT  102464
#define OFF8_MDOT  168000
#define OFF8_REJP  233536

// ---- fast path byte offsets in ws ----
#define PACKX_B  (8ull<<20)            // 16 MB packed x (hi/lo)
#define PACKC_B  (24ull<<20)           // 4 MB packed centroids
#define PACKR_B  (28ull<<20)           // 4 MB packed rejective
#define PACKT_B  (32ull<<20)           // 8 MB invden table [2000][2048] bf16
#define WS_NEED  (48ull<<20)

typedef __attribute__((ext_vector_type(8))) short bf16x8;
typedef __attribute__((ext_vector_type(4))) float f32x4;

// ===================== shared small kernels =====================
__global__ __launch_bounds__(64) void rownorm_kernel(
    const float* __restrict__ cen, const float* __restrict__ rej,
    const float* __restrict__ x, float* __restrict__ ws)
{
    int row = blockIdx.x;
    int lane = threadIdx.x;
    const float* src;
    int dstoff;
    if (row < NT)        { src = cen + (size_t)row * ND;          dstoff = OFF_NORM2C + row; }
    else if (row < 2*NT) { src = rej + (size_t)(row - NT) * ND;   dstoff = OFF_R2 + (row - NT); }
    else                 { src = x   + (size_t)(row - 2*NT) * ND; dstoff = OFF_X2 + (row - 2*NT); }
    float s = 0.f;
#pragma unroll
    for (int k = 0; k < ND / 64; ++k) { float v = src[lane + k * 64]; s += v * v; }
#pragma unroll
    for (int off = 32; off > 0; off >>= 1) s += __shfl_down(s, off);
    if (lane == 0) ws[dstoff] = s;
}

__global__ __launch_bounds__(256) void maxnorm_kernel(float* __restrict__ ws)
{
    __shared__ float sm[256];
    int tid = threadIdx.x;
    float m = 0.f;
    for (int i = tid; i < NT; i += 256) m = fmaxf(m, ws[OFF_NORM2C + i]);
    sm[tid] = m;
    __syncthreads();
    for (int s = 128; s > 0; s >>= 1) {
        if (tid < s) sm[tid] = fmaxf(sm[tid], sm[tid + s]);
        __syncthreads();
    }
    if (tid == 0) {
        float cnorm = sqrtf(sm[0]);
        float inv = 1.f / (cnorm + 1e-16f);
        ws[OFF_SCAL + 0] = cnorm;
        ws[OFF_SCAL + 1] = inv;
        ws[OFF_SCAL + 2] = inv * inv;
    }
}

// ===================== pack f32 -> split-bf16 fragment layout =====================
__device__ __forceinline__ ushort bf16rn(float f){
    uint32_t u = __float_as_uint(f);
    return (ushort)((u + 0x7fffu + ((u >> 16) & 1u)) >> 16);
}

// Layout: [rowblk128][kstep16][chunk16][lane64][16B], chunk = rsub*2 + plane(hi/lo)
__global__ __launch_bounds__(256) void pack_kernel(const float* __restrict__ src,
    unsigned char* __restrict__ dst, int validRows)
{
    int tid = threadIdx.x;
    int lane = tid & 63;
    int W = blockIdx.x * 4 + (tid >> 6);   // one wave = one (subtile, kstep)
    int s  = W >> 4;                       // 16-row subtile index
    int ks = W & 15;                       // k-step 0..15
    int row = s * 16 + (lane & 15);
    int k   = ks * 32 + (lane >> 4) * 8;
    float v[8];
    if (row < validRows) {
        float4 a = *(const float4*)&src[(size_t)row * ND + k];
        float4 b = *(const float4*)&src[(size_t)row * ND + k + 4];
        v[0]=a.x; v[1]=a.y; v[2]=a.z; v[3]=a.w;
        v[4]=b.x; v[5]=b.y; v[6]=b.z; v[7]=b.w;
    } else {
#pragma unroll
        for (int j = 0; j < 8; ++j) v[j] = 0.f;
    }
    union { ushort h[8]; uint4 q; } H, L;
#pragma unroll
    for (int j = 0; j < 8; ++j) {
        ushort hb = bf16rn(v[j]);
        float hf = __uint_as_float(((uint32_t)hb) << 16);
        H.h[j] = hb;
        L.h[j] = bf16rn(v[j] - hf);
    }
    size_t base = ((size_t)(((s >> 3) * 16 + ks) * 16 + (s & 7) * 2)) * 1024;
    *(uint4*)(dst + base + lane * 16)        = H.q;
    *(uint4*)(dst + base + 1024 + lane * 16) = L.q;
}

// ===================== LDS staging helper =====================
typedef __attribute__((address_space(3))) unsigned int lds_u32;
typedef const __attribute__((address_space(1))) unsigned int glb_u32;
__device__ __forceinline__ void gload_lds16(const unsigned char* g, unsigned char* l) {
    __builtin_amdgcn_global_load_lds((glb_u32*)g, (lds_u32*)l, 16, 0, 0);
}

#define SCHED_FENCE __builtin_amdgcn_sched_barrier(0)

#define PASS4(av, bv) do { _Pragma("unroll") \
    for (int qi = 0; qi < 4; ++qi) \
        _Pragma("unroll") \
        for (int ri = 0; ri < 4; ++ri) \
            acc[ri][qi] = __builtin_amdgcn_mfma_f32_16x16x32_bf16( \
                av[ri], bv[qi], acc[ri][qi], 0, 0, 0); \
    } while (0)

// ===================== dist core: r11 golden schedule (3-plane, 16 steps) =====================
__device__ __forceinline__ void stage_dist(
    const unsigned char* __restrict__ aP2, const unsigned char* __restrict__ bP2,
    int ks, unsigned char* lbuf, int wave, int lane)
{
    if (wave < 8) {            // A hi+lo: 32 chunks, 4 per wave
#pragma unroll
        for (int j = 0; j < 4; ++j) {
            int gc = wave * 4 + j, s = gc >> 1, pl = gc & 1;
            gload_lds16(aP2 + ((s >> 3) * 16 + ks) * 16384 + ((s & 7) * 2 + pl) * 1024 + lane * 16,
                        lbuf + gc * 1024);
        }
    } else {                   // B hi+lo: 32 chunks, 4 per wave
#pragma unroll
        for (int j = 0; j < 4; ++j) {
            int gc = (wave - 8) * 4 + j, s = gc >> 1, pl = gc & 1;
            gload_lds16(bP2 + ((s >> 3) * 16 + ks) * 16384 + ((s & 7) * 2 + pl) * 1024 + lane * 16,
                        lbuf + 32768 + gc * 1024);
        }
    }
}

__device__ __forceinline__ void compute_dist(
    const unsigned char* __restrict__ cbuf, int lane, int wr, int wc, f32x4 acc[4][4])
{
    const unsigned char* aB = cbuf + wr * 8192 + lane * 16;
    const unsigned char* bB = cbuf + 32768 + wc * 8192 + lane * 16;
    bf16x8 ah[4], bh[4];
#pragma unroll
    for (int i = 0; i < 4; ++i) {
        ah[i] = *(const bf16x8*)(aB + i * 2048);
        bh[i] = *(const bf16x8*)(bB + i * 2048);
    }
    PASS4(ah, bh);
    {
        bf16x8 bl[4];
#pragma unroll
        for (int i = 0; i < 4; ++i) bl[i] = *(const bf16x8*)(bB + i * 2048 + 1024);
        PASS4(ah, bl);
    }
    {
        bf16x8 al[4];
#pragma unroll
        for (int i = 0; i < 4; ++i) al[i] = *(const bf16x8*)(aB + i * 2048 + 1024);
        PASS4(al, bh);
    }
}

__device__ __forceinline__ void mfma_core_dist(
    const unsigned char* __restrict__ aP2, const unsigned char* __restrict__ bP2,
    unsigned char* lds, int lane, int wave, int wr, int wc, f32x4 acc[4][4])
{
    stage_dist(aP2, bP2, 0, lds, wave, lane);
    for (int ks = 0; ks < 16; ++ks) {
        unsigned char* cbuf = lds + (ks & 1) * 65536;
        unsigned char* nbuf = lds + ((ks + 1) & 1) * 65536;
        if (ks < 15) {
            stage_dist(aP2, bP2, ks + 1, nbuf, wave, lane);
            SCHED_FENCE;
            asm volatile("s_waitcnt vmcnt(4)" ::: "memory");
            SCHED_FENCE;
        } else {
            SCHED_FENCE;
            asm volatile("s_waitcnt vmcnt(0)" ::: "memory");
            SCHED_FENCE;
        }
        __builtin_amdgcn_s_barrier();
        __builtin_amdgcn_s_setprio(1);
        compute_dist(cbuf, lane, wr, wc, acc);
        __builtin_amdgcn_s_setprio(0);
        __builtin_amdgcn_s_barrier();
    }
}

// ===================== xr core: BK=64 frame (1-plane, 8 steps) =====================
__device__ __forceinline__ void stage_xr(
    const unsigned char* __restrict__ aP2, const unsigned char* __restrict__ bP2,
    int ks2, unsigned char* lbuf, int wave, int lane)
{
#pragma unroll
    for (int j = 0; j < 4; ++j) {
        int q = (wave & 7) * 4 + j;      // 0..31
        int sub = q >> 4, cs = q & 15;   // sub 0/1, chunk 0..15
        int ks = ks2 * 2 + sub;
        const unsigned char* src = (wave < 8)
            ? aP2 + ((cs >> 3) * 16 + ks) * 16384 + ((cs & 7) * 2) * 1024 + lane * 16
            : bP2 + ((cs >> 3) * 16 + ks) * 16384 + ((cs & 7) * 2) * 1024 + lane * 16;
        unsigned char* dst = lbuf + (wave < 8 ? 0 : 32768) + sub * 16384 + cs * 1024;
        gload_lds16(src, dst);
    }
}

// reads for BOTH sub-steps issued up-front; single prio region around all 32 MFMAs
__device__ __forceinline__ void compute_xr(
    const unsigned char* __restrict__ cbuf, int lane, int wr, int wc, f32x4 acc[4][4])
{
    const unsigned char* aB0 = cbuf + wr * 4096 + lane * 16;
    const unsigned char* bB0 = cbuf + 32768 + wc * 4096 + lane * 16;
    bf16x8 a0[4], b0[4], a1[4], b1[4];
#pragma unroll
    for (int i = 0; i < 4; ++i) {
        a0[i] = *(const bf16x8*)(aB0 + i * 1024);
        b0[i] = *(const bf16x8*)(bB0 + i * 1024);
        a1[i] = *(const bf16x8*)(aB0 + 16384 + i * 1024);
        b1[i] = *(const bf16x8*)(bB0 + 16384 + i * 1024);
    }
    __builtin_amdgcn_s_setprio(1);
    PASS4(a0, b0);
    PASS4(a1, b1);
    __builtin_amdgcn_s_setprio(0);
}

__device__ __forceinline__ void mfma_core_xr(
    const unsigned char* __restrict__ aP2, const unsigned char* __restrict__ bP2,
    unsigned char* lds, int lane, int wave, int wr, int wc, f32x4 acc[4][4])
{
    stage_xr(aP2, bP2, 0, lds, wave, lane);
    for (int ks2 = 0; ks2 < 8; ++ks2) {
        unsigned char* cbuf = lds + (ks2 & 1) * 65536;
        unsigned char* nbuf = lds + ((ks2 + 1) & 1) * 65536;
        if (ks2 < 7) {
            stage_xr(aP2, bP2, ks2 + 1, nbuf, wave, lane);
            SCHED_FENCE;
            asm volatile("s_waitcnt vmcnt(4)" ::: "memory");
            SCHED_FENCE;
        } else {
            SCHED_FENCE;
            asm volatile("s_waitcnt vmcnt(0)" ::: "memory");
            SCHED_FENCE;
        }
        __builtin_amdgcn_s_barrier();
        compute_xr(cbuf, lane, wr, wc, acc);
        __builtin_amdgcn_s_barrier();
    }
}

// ---------- dist: y columns + u64 d^2-key segmented argmin (3-plane, 256^2, 16 waves) ----------
__global__ __launch_bounds__(1024) void dist_mfma_kernel(
    const unsigned char* __restrict__ xpack, const unsigned char* __restrict__ cpack,
    float* __restrict__ out, float* __restrict__ ws)
{
    __shared__ unsigned char lds[2 * 65536];
    int tid = threadIdx.x, lane = tid & 63, wave = tid >> 6;
    int wr = wave >> 2, wc = wave & 3;
    int xb = blockIdx.x, yb = blockIdx.y;
    int b0 = xb * 256, t0base = yb * 256;
    f32x4 acc[4][4];
#pragma unroll
    for (int i = 0; i < 4; ++i)
#pragma unroll
        for (int q = 0; q < 4; ++q) acc[i][q] = (f32x4){0.f, 0.f, 0.f, 0.f};
    mfma_core_dist(xpack + (size_t)xb * 524288, cpack + (size_t)yb * 524288,
                   lds, lane, wave, wr, wc, acc);

    float inv  = ws[OFF_SCAL + 1];
    float inv2 = ws[OFF_SCAL + 2];
    int rq = lane >> 4, cidx = lane & 15;
    int seg = yb * 4 + wc;
    float c2q[4]; int tq[4];
#pragma unroll
    for (int qi = 0; qi < 4; ++qi) {
        int t = t0base + wc * 64 + qi * 16 + cidx;
        tq[qi] = t;
        c2q[qi] = (t < NT) ? ws[OFF_NORM2C + t] * inv2 : 0.f;
    }
    unsigned long long* keys = (unsigned long long*)(ws + NOFF_MIND);

#pragma unroll
    for (int ri = 0; ri < 4; ++ri) {
#pragma unroll
        for (int reg = 0; reg < 4; ++reg) {
            int row = b0 + wr * 64 + ri * 16 + rq * 4 + reg;
            float x2 = ws[OFF_X2 + row];
            unsigned long long best = ~0ull;
#pragma unroll
            for (int qi = 0; qi < 4; ++qi) {
                float d2 = fmaxf(x2 + c2q[qi] - 2.f * (acc[ri][qi][reg] * inv), 0.f);
                float d2n = __shfl_xor(d2, 1);   // partner t^1 for per-class pair min
                int t = tq[qi];
                if ((t < NT) && ((cidx & 1) == 0))
                    out[(size_t)row * OUTW + (t >> 1)] = -sqrtf(fminf(d2, d2n));
                if (t < NT) {
                    unsigned long long key =
                        ((unsigned long long)__float_as_uint(d2) << 32) | (unsigned)t;
                    best = best < key ? best : key;
                }
            }
#pragma unroll
            for (int off = 1; off < 16; off <<= 1) {
                unsigned long long o = __shfl_xor(best, off);
                best = best < o ? best : o;
            }
            if (cidx == 0) keys[(size_t)row * 32 + seg] = best;
        }
    }
}

// ---------- combine: u64 d^2-keys -> idx, cx (exact recovery), cl2 ----------
__global__ __launch_bounds__(256) void combine32_kernel(float* __restrict__ ws)
{
    int b = blockIdx.x * 256 + threadIdx.x;
    const unsigned long long* keys = (const unsigned long long*)(ws + NOFF_MIND);
    unsigned long long best = keys[(size_t)b * 32];
#pragma unroll
    for (int s = 1; s < 32; ++s) {
        unsigned long long k = keys[(size_t)b * 32 + s];
        best = best < k ? best : k;
    }
    int bt = (int)(best & 0xffffffffull);
    float d2 = __uint_as_float((unsigned)(best >> 32));
    float c2 = ws[OFF_NORM2C + bt] * ws[OFF_SCAL + 2];
    float x2 = ws[OFF_X2 + b];
    ((int*)ws)[OFF_IDX + b] = bt;
    ws[OFF_CX + b] = 0.5f * (x2 + c2 - d2);   // dot = (x2+c2-d^2)/2
    ws[OFF_CL2 + b] = c2;
}

// ===================== 128^2 register-core, 1-plane (for table) =====================
#define LOADA1(buf, ks_) do { _Pragma("unroll") \
    for (int i = 0; i < 4; ++i) { \
        buf[i] = *(const bf16x8*)(aB + (ks_) * 16384 + i * 2048); \
    } } while (0)
#define LOADB1(buf, ks_) do { _Pragma("unroll") \
    for (int i = 0; i < 4; ++i) { \
        buf[i] = *(const bf16x8*)(bB + (ks_) * 16384 + i * 2048); \
    } } while (0)

__device__ __forceinline__ void mfma_core_db1(
    const unsigned char* __restrict__ aP, const unsigned char* __restrict__ bP,
    int lane, int wr, int wc, f32x4 acc[4][4])
{
    const unsigned char* aB = aP + wr * 8192 + lane * 16;
    const unsigned char* bB = bP + wc * 8192 + lane * 16;
    bf16x8 a0[4], a1[4], b0[4], b1[4];
    LOADA1(a0, 0); LOADB1(b0, 0);
    for (int ks = 0; ks < 16; ks += 2) {
        LOADA1(a1, ks + 1); LOADB1(b1, ks + 1);
        PASS4(a0, b0);
        if (ks + 2 < 16) { LOADA1(a0, ks + 2); LOADB1(b0, ks + 2); }
        PASS4(a1, b1);
    }
}

// ---------- invden table (bf16): 1/(||cf[c]-r[t]|| + 1e-9), [c][t] stride 2048 ----------
__global__ __launch_bounds__(256, 2) void table_mfma_kernel(
    const unsigned char* __restrict__ cpack, const unsigned char* __restrict__ rpack,
    ushort* __restrict__ table, const float* __restrict__ ws)
{
    int tid = threadIdx.x, lane = tid & 63, wave = tid >> 6;
    int wr = wave >> 1, wc = wave & 1;
    int c0 = blockIdx.x * 128, t0base = blockIdx.y * 128;
    f32x4 acc[4][4];
#pragma unroll
    for (int i = 0; i < 4; ++i)
#pragma unroll
        for (int q = 0; q < 4; ++q) acc[i][q] = (f32x4){0.f, 0.f, 0.f, 0.f};
    mfma_core_db1(cpack + (size_t)blockIdx.x * 262144, rpack + (size_t)blockIdx.y * 262144,
                  lane, wr, wc, acc);

    float inv  = ws[OFF_SCAL + 1];
    float inv2 = ws[OFF_SCAL + 2];
    int rq = lane >> 4, cidx = lane & 15;
    float r2q[4]; int tq[4];
#pragma unroll
    for (int qi = 0; qi < 4; ++qi) {
        int t = t0base + wc * 64 + qi * 16 + cidx;
        tq[qi] = t;
        r2q[qi] = (t < NT) ? ws[OFF_R2 + t] : 0.f;
    }
#pragma unroll
    for (int ri = 0; ri < 4; ++ri) {
#pragma unroll
        for (int reg = 0; reg < 4; ++reg) {
            int c = c0 + wr * 64 + ri * 16 + rq * 4 + reg;
            if (c < NT) {
                float cl2c = ws[OFF_NORM2C + c] * inv2;
#pragma unroll
                for (int qi = 0; qi < 4; ++qi) {
                    int t = tq[qi];
                    if (t < NT) {
                        float cfr = acc[ri][qi][reg] * inv;
                        float den = sqrtf(fmaxf(cl2c + r2q[qi] - 2.f * cfr, 0.f)) + 1e-9f;
                        table[(size_t)c * 2048 + t] = bf16rn(1.f / den);
                    }
                }
            }
        }
    }
}

// ---------- xr GEMM + rejective min via bf16 table gather (1-plane, BK=64, 16 waves) ----------
__global__ __launch_bounds__(1024) void xr_mfma_kernel(
    const unsigned char* __restrict__ xpack, const unsigned char* __restrict__ rpack,
    const ushort* __restrict__ table, float* __restrict__ ws)
{
    __shared__ unsigned char lds[2 * 65536];
    int tid = threadIdx.x, lane = tid & 63, wave = tid >> 6;
    int wr = wave >> 2, wc = wave & 3;
    int xb = blockIdx.x, yb = blockIdx.y;
    int b0 = xb * 256, t0base = yb * 256;
    f32x4 acc[4][4];
#pragma unroll
    for (int i = 0; i < 4; ++i)
#pragma unroll
        for (int q = 0; q < 4; ++q) acc[i][q] = (f32x4){0.f, 0.f, 0.f, 0.f};
    mfma_core_xr(xpack + (size_t)xb * 524288, rpack + (size_t)yb * 524288,
                 lds, lane, wave, wr, wc, acc);

    int rq = lane >> 4, cidx = lane & 15;
    int seg = yb * 4 + wc;
    float r2q[4]; int tq[4];
#pragma unroll
    for (int qi = 0; qi < 4; ++qi) {
        int t = t0base + wc * 64 + qi * 16 + cidx;
        tq[qi] = t;
        r2q[qi] = (t < NT) ? ws[OFF_R2 + t] : 0.f;
    }
#pragma unroll
    for (int ri = 0; ri < 4; ++ri) {
#pragma unroll
        for (int reg = 0; reg < 4; ++reg) {
            int row = b0 + wr * 64 + ri * 16 + rq * 4 + reg;
            int idx = ((const int*)ws)[OFF_IDX + row];
            float cx  = ws[OFF_CX + row];
            float cl2 = ws[OFF_CL2 + row];
            const ushort* trow = table + (size_t)idx * 2048;
            float tv[4];
#pragma unroll
            for (int qi = 0; qi < 4; ++qi)
                tv[qi] = (tq[qi] < NT)
                    ? __uint_as_float(((uint32_t)trow[tq[qi]]) << 16) : 0.f;
            float mv = INFINITY;
#pragma unroll
            for (int qi = 0; qi < 4; ++qi) {
                if (tq[qi] < NT) {
                    float num = fabsf(cx - acc[ri][qi][reg] - 0.5f * (cl2 - r2q[qi]));
                    mv = fminf(mv, num * tv[qi]);
                }
            }
#pragma unroll
            for (int off = 1; off < 16; off <<= 1) mv = fminf(mv, __shfl_xor(mv, off));
            if (cidx == 0) ws[NOFF_REJP + (size_t)row * 32 + seg] = mv;
        }
    }
}

__global__ __launch_bounds__(256) void rejcombine32_kernel(
    const float* __restrict__ ws, float* __restrict__ out)
{
    int b = blockIdx.x * 256 + threadIdx.x;
    float bd = ws[NOFF_REJP + (size_t)b * 32];
#pragma unroll
    for (int s = 1; s < 32; ++s) bd = fminf(bd, ws[NOFF_REJP + (size_t)b * 32 + s]);
    out[(size_t)b * OUTW + NCLS] = bd;
}

// ===================== fallback path (round-1 f32 VALU pipeline) =====================
#define BK   32
#define LDST 68

__global__ __launch_bounds__(256) void dist_kernel(
    const float* __restrict__ x, const float* __restrict__ cen,
    float* __restrict__ out, float* __restrict__ ws)
{
    __shared__ float Xs[BK][LDST];
    __shared__ float Cs[BK][LDST];
    __shared__ float red_d[64][17];
    __shared__ int   red_t[64][17];
    __shared__ float red_x[64][17];

    int tid = threadIdx.x;
    int tx = tid & 15, ty = tid >> 4;
    int b0 = blockIdx.x * 64;
    int tseg0 = blockIdx.y * 256;
    int tseg1 = min(tseg0 + 256, NT);

    float inv  = ws[OFF_SCAL + 1];
    float inv2 = ws[OFF_SCAL + 2];
    float x2v[4];
#pragma unroll
    for (int i = 0; i < 4; ++i) x2v[i] = ws[OFF_X2 + b0 + ty * 4 + i];

    int lr = tid >> 2;
    int lc = (tid & 3) * 8;

    float mind[4], mdot[4];
    int mint[4];
#pragma unroll
    for (int i = 0; i < 4; ++i) { mind[i] = INFINITY; mint[i] = 0x7fffffff; mdot[i] = 0.f; }

    for (int t0 = tseg0; t0 < tseg1; t0 += 64) {
        float acc[4][4];
#pragma unroll
        for (int i = 0; i < 4; ++i)
#pragma unroll
            for (int jj = 0; jj < 4; ++jj) acc[i][jj] = 0.f;

        for (int k0 = 0; k0 < ND; k0 += BK) {
            {
                const float4 v0 = *(const float4*)&x[(size_t)(b0 + lr) * ND + k0 + lc];
                const float4 v1 = *(const float4*)&x[(size_t)(b0 + lr) * ND + k0 + lc + 4];
                Xs[lc + 0][lr] = v0.x; Xs[lc + 1][lr] = v0.y; Xs[lc + 2][lr] = v0.z; Xs[lc + 3][lr] = v0.w;
                Xs[lc + 4][lr] = v1.x; Xs[lc + 5][lr] = v1.y; Xs[lc + 6][lr] = v1.z; Xs[lc + 7][lr] = v1.w;
            }
            {
                int tr = t0 + lr;
                float4 v0 = make_float4(0.f, 0.f, 0.f, 0.f), v1 = v0;
                if (tr < NT) {
                    v0 = *(const float4*)&cen[(size_t)tr * ND + k0 + lc];
                    v1 = *(const float4*)&cen[(size_t)tr * ND + k0 + lc + 4];
                }
                Cs[lc + 0][lr] = v0.x; Cs[lc + 1][lr] = v0.y; Cs[lc + 2][lr] = v0.z; Cs[lc + 3][lr] = v0.w;
                Cs[lc + 4][lr] = v1.x; Cs[lc + 5][lr] = v1.y; Cs[lc + 6][lr] = v1.z; Cs[lc + 7][lr] = v1.w;
            }
            __syncthreads();
#pragma unroll
            for (int kk = 0; kk < BK; ++kk) {
                float4 av = *(const float4*)&Xs[kk][ty * 4];
                float4 bv = *(const float4*)&Cs[kk][tx * 4];
                float a[4] = {av.x, av.y, av.z, av.w};
                float bb[4] = {bv.x, bv.y, bv.z, bv.w};
#pragma unroll
                for (int i = 0; i < 4; ++i)
#pragma unroll
                    for (int jj = 0; jj < 4; ++jj)
                        acc[i][jj] = fmaf(a[i], bb[jj], acc[i][jj]);
            }
            __syncthreads();
        }

        float distv[4][4];
#pragma unroll
        for (int jj = 0; jj < 4; ++jj) {
            int t = t0 + tx * 4 + jj;
            bool valid = (t < NT);
            float c2 = valid ? ws[OFF_NORM2C + t] * inv2 : 0.f;
#pragma unroll
            for (int i = 0; i < 4; ++i) {
                float dsc = acc[i][jj] * inv;
                float d2 = x2v[i] + c2 - 2.f * dsc;
                float dd = sqrtf(fmaxf(d2, 0.f));
                distv[i][jj] = dd;
                if (valid && (dd < mind[i])) { mind[i] = dd; mint[i] = t; mdot[i] = dsc; }
            }
        }
#pragma unroll
        for (int jp = 0; jp < 2; ++jp) {
            int t = t0 + tx * 4 + jp * 2;
            if (t < NT) {
                int cls = t >> 1;
#pragma unroll
                for (int i = 0; i < 4; ++i) {
                    out[(size_t)(b0 + ty * 4 + i) * OUTW + cls] =
                        -fminf(distv[i][jp * 2], distv[i][jp * 2 + 1]);
                }
            }
        }
    }

#pragma unroll
    for (int i = 0; i < 4; ++i) {
        red_d[ty * 4 + i][tx] = mind[i];
        red_t[ty * 4 + i][tx] = mint[i];
        red_x[ty * 4 + i][tx] = mdot[i];
    }
    __syncthreads();
    if (tid < 64) {
        float bd = red_d[tid][0]; int bt = red_t[tid][0]; float bx = red_x[tid][0];
        for (int q = 1; q < 16; ++q) {
            float d = red_d[tid][q]; int tt = red_t[tid][q];
            if (d < bd || (d == bd && tt < bt)) { bd = d; bt = tt; bx = red_x[tid][q]; }
        }
        int b = b0 + tid;
        int s = blockIdx.y;
        ws[OFF8_MIND + b * 8 + s] = bd;
        ((int*)ws)[OFF8_MINT + b * 8 + s] = bt;
        ws[OFF8_MDOT + b * 8 + s] = bx;
    }
}

__global__ __launch_bounds__(256) void combine_kernel(float* __restrict__ ws)
{
    int b = blockIdx.x * 256 + threadIdx.x;
    float bd = ws[OFF8_MIND + b * 8];
    int   bt = ((int*)ws)[OFF8_MINT + b * 8];
    float bx = ws[OFF8_MDOT + b * 8];
#pragma unroll
    for (int s = 1; s < 8; ++s) {
        float d = ws[OFF8_MIND + b * 8 + s];
        int  tt = ((int*)ws)[OFF8_MINT + b * 8 + s];
        if (d < bd || (d == bd && tt < bt)) { bd = d; bt = tt; bx = ws[OFF8_MDOT + b * 8 + s]; }
    }
    ((int*)ws)[OFF_IDX + b] = bt;
    ws[OFF_CX + b] = bx;
    ws[OFF_CL2 + b] = ws[OFF_NORM2C + bt] * ws[OFF_SCAL + 2];
}

__global__ __launch_bounds__(256) void rej_kernel(
    const float* __restrict__ x, const float* __restrict__ cen,
    const float* __restrict__ rej, float* __restrict__ ws)
{
    __shared__ float Xs[BK][LDST];
    __shared__ float Rs[BK][LDST];
    __shared__ float Ls[BK][LDST];
    __shared__ int idxL[64];
    __shared__ float red_d[64][17];

    int tid = threadIdx.x;
    int tx = tid & 15, ty = tid >> 4;
    int b0 = blockIdx.x * 64;
    int tseg0 = blockIdx.y * 256;
    int tseg1 = min(tseg0 + 256, NT);
    float inv = ws[OFF_SCAL + 1];

    if (tid < 64) idxL[tid] = ((int*)ws)[OFF_IDX + b0 + tid];
    float cxv[4], cl2v[4];
#pragma unroll
    for (int i = 0; i < 4; ++i) {
        cxv[i]  = ws[OFF_CX  + b0 + ty * 4 + i];
        cl2v[i] = ws[OFF_CL2 + b0 + ty * 4 + i];
    }
    __syncthreads();

    int lr = tid >> 2, lc = (tid & 3) * 8;
    int myrow = idxL[lr];

    float minv[4] = {INFINITY, INFINITY, INFINITY, INFINITY};

    for (int t0 = tseg0; t0 < tseg1; t0 += 64) {
        float xr[4][4], cr[4][4];
#pragma unroll
        for (int i = 0; i < 4; ++i)
#pragma unroll
            for (int jj = 0; jj < 4; ++jj) { xr[i][jj] = 0.f; cr[i][jj] = 0.f; }

        for (int k0 = 0; k0 < ND; k0 += BK) {
            {
                const float4 v0 = *(const float4*)&x[(size_t)(b0 + lr) * ND + k0 + lc];
                const float4 v1 = *(const float4*)&x[(size_t)(b0 + lr) * ND + k0 + lc + 4];
                Xs[lc + 0][lr] = v0.x; Xs[lc + 1][lr] = v0.y; Xs[lc + 2][lr] = v0.z; Xs[lc + 3][lr] = v0.w;
                Xs[lc + 4][lr] = v1.x; Xs[lc + 5][lr] = v1.y; Xs[lc + 6][lr] = v1.z; Xs[lc + 7][lr] = v1.w;
            }
            {
                const float4 v0 = *(const float4*)&cen[(size_t)myrow * ND + k0 + lc];
                const float4 v1 = *(const float4*)&cen[(size_t)myrow * ND + k0 + lc + 4];
                Ls[lc + 0][lr] = v0.x * inv; Ls[lc + 1][lr] = v0.y * inv;
                Ls[lc + 2][lr] = v0.z * inv; Ls[lc + 3][lr] = v0.w * inv;
                Ls[lc + 4][lr] = v1.x * inv; Ls[lc + 5][lr] = v1.y * inv;
                Ls[lc + 6][lr] = v1.z * inv; Ls[lc + 7][lr] = v1.w * inv;
            }
            {
                int tr = t0 + lr;
                float4 v0 = make_float4(0.f, 0.f, 0.f, 0.f), v1 = v0;
                if (tr < NT) {
                    v0 = *(const float4*)&rej[(size_t)tr * ND + k0 + lc];
                    v1 = *(const float4*)&rej[(size_t)tr * ND + k0 + lc + 4];
                }
                Rs[lc + 0][lr] = v0.x; Rs[lc + 1][lr] = v0.y; Rs[lc + 2][lr] = v0.z; Rs[lc + 3][lr] = v0.w;
                Rs[lc + 4][lr] = v1.x; Rs[lc + 5][lr] = v1.y; Rs[lc + 6][lr] = v1.z; Rs[lc + 7][lr] = v1.w;
            }
            __syncthreads();
#pragma unroll
            for (int kk = 0; kk < BK; ++kk) {
                float4 av = *(const float4*)&Xs[kk][ty * 4];
                float4 lv = *(const float4*)&Ls[kk][ty * 4];
                float4 rv = *(const float4*)&Rs[kk][tx * 4];
                float a[4] = {av.x, av.y, av.z, av.w};
                float l[4] = {lv.x, lv.y, lv.z, lv.w};
                float r[4] = {rv.x, rv.y, rv.z, rv.w};
#pragma unroll
                for (int i = 0; i < 4; ++i)
#pragma unroll
                    for (int jj = 0; jj < 4; ++jj) {
                        xr[i][jj] = fmaf(a[i], r[jj], xr[i][jj]);
                        cr[i][jj] = fmaf(l[i], r[jj], cr[i][jj]);
                    }
            }
            __syncthreads();
        }

#pragma unroll
        for (int jj = 0; jj < 4; ++jj) {
            int t = t0 + tx * 4 + jj;
            if (t < NT) {
                float r2 = ws[OFF_R2 + t];
#pragma unroll
                for (int i = 0; i < 4; ++i) {
                    float num = fabsf(cxv[i] - xr[i][jj] - 0.5f * (cl2v[i] - r2));
                    float den = sqrtf(fmaxf(cl2v[i] + r2 - 2.f * cr[i][jj], 0.f)) + 1e-9f;
                    minv[i] = fminf(minv[i], num / den);
                }
            }
        }
    }

#pragma unroll
    for (int i = 0; i < 4; ++i) red_d[ty * 4 + i][tx] = minv[i];
    __syncthreads();
    if (tid < 64) {
        float bd = red_d[tid][0];
        for (int q = 1; q < 16; ++q) bd = fminf(bd, red_d[tid][q]);
        ws[OFF8_REJP + (size_t)(b0 + tid) * 8 + blockIdx.y] = bd;
    }
}

__global__ __launch_bounds__(256) void rejcombine_kernel(
    const float* __restrict__ ws, float* __restrict__ out)
{
    int b = blockIdx.x * 256 + threadIdx.x;
    float bd = ws[OFF8_REJP + b * 8];
#pragma unroll
    for (int s = 1; s < 8; ++s) bd = fminf(bd, ws[OFF8_REJP + b * 8 + s]);
    out[(size_t)b * OUTW + NCLS] = bd;
}

// ===================== launch =====================
extern "C" void kernel_launch(void* const* d_in, const int* in_sizes, int n_in,
                              void* d_out, int out_size, void* d_ws, size_t ws_size,
                              hipStream_t stream)
{
    const float* x   = (const float*)d_in[0];
    const float* cen = (const float*)d_in[1];
    const float* rej = (const float*)d_in[2];
    float* out = (float*)d_out;
    float* ws  = (float*)d_ws;
    unsigned char* wsb = (unsigned char*)d_ws;

    rownorm_kernel<<<2 * NT + NB, 64, 0, stream>>>(cen, rej, x, ws);
    maxnorm_kernel<<<1, 256, 0, stream>>>(ws);

    if (ws_size >= WS_NEED) {
        // fast path (best measured config): dist r11-golden 3-plane 256^2 16-wave;
        // xr BK=64 1-plane; bf16 invden table; u64-key argmin
        pack_kernel<<<2048, 256, 0, stream>>>(x,   wsb + PACKX_B, NB);
        pack_kernel<<<512,  256, 0, stream>>>(cen, wsb + PACKC_B, NT);
        pack_kernel<<<512,  256, 0, stream>>>(rej, wsb + PACKR_B, NT);
        dist_mfma_kernel<<<dim3(32, 8), 1024, 0, stream>>>(wsb + PACKX_B, wsb + PACKC_B, out, ws);
        combine32_kernel<<<32, 256, 0, stream>>>(ws);
        table_mfma_kernel<<<dim3(16, 16), 256, 0, stream>>>(wsb + PACKC_B, wsb + PACKR_B,
                                                            (ushort*)(wsb + PACKT_B), ws);
        xr_mfma_kernel<<<dim3(32, 8), 1024, 0, stream>>>(wsb + PACKX_B, wsb + PACKR_B,
                                                         (const ushort*)(wsb + PACKT_B), ws);
        rejcombine32_kernel<<<32, 256, 0, stream>>>(ws, out);
    } else {
        // fallback: round-1 f32 VALU pipeline
        dist_kernel<<<dim3(NB / 64, 8), 256, 0, stream>>>(x, cen, out, ws);
        combine_kernel<<<NB / 256, 256, 0, stream>>>(ws);
        rej_kernel<<<dim3(NB / 64, 8), 256, 0, stream>>>(x, cen, rej, ws);
        rejcombine_kernel<<<NB / 256, 256, 0, stream>>>(ws, out);
    }
}

// Round 17
// 153.007 us; speedup vs baseline: 1.1406x; 1.1406x over previous
//
#include <hip/hip_runtime.h>
#include <math.h>
#include <stdint.h>

// Problem constants: B=8192, C=1000, N=2, D=512, return_dists=1
#define NB   8192
#define NCLS 1000
#define NT   2000   // C*N
#define ND   512
#define OUTW 1001

// ---- shared ws scalar layout (float offsets) ----
#define OFF_NORM2C 0        // [2048] centroid row |.|^2 (raw)
#define OFF_R2     2048     // [2048] rejective row |.|^2
#define OFF_X2     4096     // [8192] x row |.|^2
#define OFF_SCAL   12288    // [0]=cnorm [1]=inv [2]=inv^2
#define OFF_IDX    12352    // [8192] int argmin t
#define OFF_CX     20544    // [8192] x.cf[idx]
#define OFF_CL2    28736    // [8192] |cf[idx]|^2

// ---- fast path: u64 argmin keys [8192][32] ----
#define NOFF_MIND  36928    // u64 keys (2 MB)
#define NOFF_REJP  823360   // [8192*32] float

// ---- fallback path (8 segments) ----
#define OFF8_MIND  36928
#define OFF8_MINT  102464
#define OFF8_MDOT  168000
#define OFF8_REJP  233536

// ---- fast path byte offsets in ws ----
#define PACKX_B  (8ull<<20)            // 16 MB packed x (hi/lo)
#define PACKC_B  (24ull<<20)           // 4 MB packed centroids
#define PACKR_B  (28ull<<20)           // 4 MB packed rejective
#define PACKT_B  (32ull<<20)           // 8 MB invden table [2000][2048] bf16
#define WS_NEED  (48ull<<20)

typedef __attribute__((ext_vector_type(8))) short bf16x8;
typedef __attribute__((ext_vector_type(4))) float f32x4;

// ===================== shared small kernels =====================
__global__ __launch_bounds__(64) void rownorm_kernel(
    const float* __restrict__ cen, const float* __restrict__ rej,
    const float* __restrict__ x, float* __restrict__ ws)
{
    int row = blockIdx.x;
    int lane = threadIdx.x;
    const float* src;
    int dstoff;
    if (row < NT)        { src = cen + (size_t)row * ND;          dstoff = OFF_NORM2C + row; }
    else if (row < 2*NT) { src = rej + (size_t)(row - NT) * ND;   dstoff = OFF_R2 + (row - NT); }
    else                 { src = x   + (size_t)(row - 2*NT) * ND; dstoff = OFF_X2 + (row - 2*NT); }
    float s = 0.f;
#pragma unroll
    for (int k = 0; k < ND / 64; ++k) { float v = src[lane + k * 64]; s += v * v; }
#pragma unroll
    for (int off = 32; off > 0; off >>= 1) s += __shfl_down(s, off);
    if (lane == 0) ws[dstoff] = s;
}

__global__ __launch_bounds__(256) void maxnorm_kernel(float* __restrict__ ws)
{
    __shared__ float sm[256];
    int tid = threadIdx.x;
    float m = 0.f;
    for (int i = tid; i < NT; i += 256) m = fmaxf(m, ws[OFF_NORM2C + i]);
    sm[tid] = m;
    __syncthreads();
    for (int s = 128; s > 0; s >>= 1) {
        if (tid < s) sm[tid] = fmaxf(sm[tid], sm[tid + s]);
        __syncthreads();
    }
    if (tid == 0) {
        float cnorm = sqrtf(sm[0]);
        float inv = 1.f / (cnorm + 1e-16f);
        ws[OFF_SCAL + 0] = cnorm;
        ws[OFF_SCAL + 1] = inv;
        ws[OFF_SCAL + 2] = inv * inv;
    }
}

// ===================== pack f32 -> split-bf16 fragment layout =====================
__device__ __forceinline__ ushort bf16rn(float f){
    uint32_t u = __float_as_uint(f);
    return (ushort)((u + 0x7fffu + ((u >> 16) & 1u)) >> 16);
}

// Layout: [rowblk128][kstep16][chunk16][lane64][16B], chunk = rsub*2 + plane(hi/lo)
__global__ __launch_bounds__(256) void pack_kernel(const float* __restrict__ src,
    unsigned char* __restrict__ dst, int validRows)
{
    int tid = threadIdx.x;
    int lane = tid & 63;
    int W = blockIdx.x * 4 + (tid >> 6);   // one wave = one (subtile, kstep)
    int s  = W >> 4;                       // 16-row subtile index
    int ks = W & 15;                       // k-step 0..15
    int row = s * 16 + (lane & 15);
    int k   = ks * 32 + (lane >> 4) * 8;
    float v[8];
    if (row < validRows) {
        float4 a = *(const float4*)&src[(size_t)row * ND + k];
        float4 b = *(const float4*)&src[(size_t)row * ND + k + 4];
        v[0]=a.x; v[1]=a.y; v[2]=a.z; v[3]=a.w;
        v[4]=b.x; v[5]=b.y; v[6]=b.z; v[7]=b.w;
    } else {
#pragma unroll
        for (int j = 0; j < 8; ++j) v[j] = 0.f;
    }
    union { ushort h[8]; uint4 q; } H, L;
#pragma unroll
    for (int j = 0; j < 8; ++j) {
        ushort hb = bf16rn(v[j]);
        float hf = __uint_as_float(((uint32_t)hb) << 16);
        H.h[j] = hb;
        L.h[j] = bf16rn(v[j] - hf);
    }
    size_t base = ((size_t)(((s >> 3) * 16 + ks) * 16 + (s & 7) * 2)) * 1024;
    *(uint4*)(dst + base + lane * 16)        = H.q;
    *(uint4*)(dst + base + 1024 + lane * 16) = L.q;
}

// ===================== LDS staging helper =====================
typedef __attribute__((address_space(3))) unsigned int lds_u32;
typedef const __attribute__((address_space(1))) unsigned int glb_u32;
__device__ __forceinline__ void gload_lds16(const unsigned char* g, unsigned char* l) {
    __builtin_amdgcn_global_load_lds((glb_u32*)g, (lds_u32*)l, 16, 0, 0);
}

#define SCHED_FENCE __builtin_amdgcn_sched_barrier(0)

#define PASS4(av, bv) do { _Pragma("unroll") \
    for (int qi = 0; qi < 4; ++qi) \
        _Pragma("unroll") \
        for (int ri = 0; ri < 4; ++ri) \
            acc[ri][qi] = __builtin_amdgcn_mfma_f32_16x16x32_bf16( \
                av[ri], bv[qi], acc[ri][qi], 0, 0, 0); \
    } while (0)

// ===================== dist core: r11 golden schedule (3-plane, 16 steps) =====================
__device__ __forceinline__ void stage_dist(
    const unsigned char* __restrict__ aP2, const unsigned char* __restrict__ bP2,
    int ks, unsigned char* lbuf, int wave, int lane)
{
    if (wave < 8) {            // A hi+lo: 32 chunks, 4 per wave
#pragma unroll
        for (int j = 0; j < 4; ++j) {
            int gc = wave * 4 + j, s = gc >> 1, pl = gc & 1;
            gload_lds16(aP2 + ((s >> 3) * 16 + ks) * 16384 + ((s & 7) * 2 + pl) * 1024 + lane * 16,
                        lbuf + gc * 1024);
        }
    } else {                   // B hi+lo: 32 chunks, 4 per wave
#pragma unroll
        for (int j = 0; j < 4; ++j) {
            int gc = (wave - 8) * 4 + j, s = gc >> 1, pl = gc & 1;
            gload_lds16(bP2 + ((s >> 3) * 16 + ks) * 16384 + ((s & 7) * 2 + pl) * 1024 + lane * 16,
                        lbuf + 32768 + gc * 1024);
        }
    }
}

__device__ __forceinline__ void compute_dist(
    const unsigned char* __restrict__ cbuf, int lane, int wr, int wc, f32x4 acc[4][4])
{
    const unsigned char* aB = cbuf + wr * 8192 + lane * 16;
    const unsigned char* bB = cbuf + 32768 + wc * 8192 + lane * 16;
    bf16x8 ah[4], bh[4];
#pragma unroll
    for (int i = 0; i < 4; ++i) {
        ah[i] = *(const bf16x8*)(aB + i * 2048);
        bh[i] = *(const bf16x8*)(bB + i * 2048);
    }
    PASS4(ah, bh);
    {
        bf16x8 bl[4];
#pragma unroll
        for (int i = 0; i < 4; ++i) bl[i] = *(const bf16x8*)(bB + i * 2048 + 1024);
        PASS4(ah, bl);
    }
    {
        bf16x8 al[4];
#pragma unroll
        for (int i = 0; i < 4; ++i) al[i] = *(const bf16x8*)(aB + i * 2048 + 1024);
        PASS4(al, bh);
    }
}

__device__ __forceinline__ void mfma_core_dist(
    const unsigned char* __restrict__ aP2, const unsigned char* __restrict__ bP2,
    unsigned char* lds, int lane, int wave, int wr, int wc, f32x4 acc[4][4])
{
    stage_dist(aP2, bP2, 0, lds, wave, lane);
    for (int ks = 0; ks < 16; ++ks) {
        unsigned char* cbuf = lds + (ks & 1) * 65536;
        unsigned char* nbuf = lds + ((ks + 1) & 1) * 65536;
        if (ks < 15) {
            stage_dist(aP2, bP2, ks + 1, nbuf, wave, lane);
            SCHED_FENCE;
            asm volatile("s_waitcnt vmcnt(4)" ::: "memory");
            SCHED_FENCE;
        } else {
            SCHED_FENCE;
            asm volatile("s_waitcnt vmcnt(0)" ::: "memory");
            SCHED_FENCE;
        }
        __builtin_amdgcn_s_barrier();
        __builtin_amdgcn_s_setprio(1);
        compute_dist(cbuf, lane, wr, wc, acc);
        __builtin_amdgcn_s_setprio(0);
        __builtin_amdgcn_s_barrier();
    }
}

// ===================== xr core: BK=64 frame (1-plane, 8 steps) =====================
__device__ __forceinline__ void stage_xr(
    const unsigned char* __restrict__ aP2, const unsigned char* __restrict__ bP2,
    int ks2, unsigned char* lbuf, int wave, int lane)
{
#pragma unroll
    for (int j = 0; j < 4; ++j) {
        int q = (wave & 7) * 4 + j;      // 0..31
        int sub = q >> 4, cs = q & 15;   // sub 0/1, chunk 0..15
        int ks = ks2 * 2 + sub;
        const unsigned char* src = (wave < 8)
            ? aP2 + ((cs >> 3) * 16 + ks) * 16384 + ((cs & 7) * 2) * 1024 + lane * 16
            : bP2 + ((cs >> 3) * 16 + ks) * 16384 + ((cs & 7) * 2) * 1024 + lane * 16;
        unsigned char* dst = lbuf + (wave < 8 ? 0 : 32768) + sub * 16384 + cs * 1024;
        gload_lds16(src, dst);
    }
}

__device__ __forceinline__ void compute_xr(
    const unsigned char* __restrict__ cbuf, int lane, int wr, int wc, f32x4 acc[4][4])
{
#pragma unroll
    for (int sub = 0; sub < 2; ++sub) {
        const unsigned char* aB = cbuf + sub * 16384 + wr * 4096 + lane * 16;
        const unsigned char* bB = cbuf + 32768 + sub * 16384 + wc * 4096 + lane * 16;
        bf16x8 ah[4], bh[4];
#pragma unroll
        for (int i = 0; i < 4; ++i) {
            ah[i] = *(const bf16x8*)(aB + i * 1024);
            bh[i] = *(const bf16x8*)(bB + i * 1024);
        }
        __builtin_amdgcn_s_setprio(1);
        PASS4(ah, bh);
        __builtin_amdgcn_s_setprio(0);
    }
}

__device__ __forceinline__ void mfma_core_xr(
    const unsigned char* __restrict__ aP2, const unsigned char* __restrict__ bP2,
    unsigned char* lds, int lane, int wave, int wr, int wc, f32x4 acc[4][4])
{
    stage_xr(aP2, bP2, 0, lds, wave, lane);
    for (int ks2 = 0; ks2 < 8; ++ks2) {
        unsigned char* cbuf = lds + (ks2 & 1) * 65536;
        unsigned char* nbuf = lds + ((ks2 + 1) & 1) * 65536;
        if (ks2 < 7) {
            stage_xr(aP2, bP2, ks2 + 1, nbuf, wave, lane);
            SCHED_FENCE;
            asm volatile("s_waitcnt vmcnt(4)" ::: "memory");
            SCHED_FENCE;
        } else {
            SCHED_FENCE;
            asm volatile("s_waitcnt vmcnt(0)" ::: "memory");
            SCHED_FENCE;
        }
        __builtin_amdgcn_s_barrier();
        compute_xr(cbuf, lane, wr, wc, acc);
        __builtin_amdgcn_s_barrier();
    }
}

// ---------- dist: y columns + u64 d^2-key segmented argmin (3-plane, 256^2, 16 waves) ----------
__global__ __launch_bounds__(1024) void dist_mfma_kernel(
    const unsigned char* __restrict__ xpack, const unsigned char* __restrict__ cpack,
    float* __restrict__ out, float* __restrict__ ws)
{
    __shared__ unsigned char lds[2 * 65536];
    int tid = threadIdx.x, lane = tid & 63, wave = tid >> 6;
    int wr = wave >> 2, wc = wave & 3;
    int xb = blockIdx.x, yb = blockIdx.y;
    int b0 = xb * 256, t0base = yb * 256;
    f32x4 acc[4][4];
#pragma unroll
    for (int i = 0; i < 4; ++i)
#pragma unroll
        for (int q = 0; q < 4; ++q) acc[i][q] = (f32x4){0.f, 0.f, 0.f, 0.f};
    mfma_core_dist(xpack + (size_t)xb * 524288, cpack + (size_t)yb * 524288,
                   lds, lane, wave, wr, wc, acc);

    float inv  = ws[OFF_SCAL + 1];
    float inv2 = ws[OFF_SCAL + 2];
    int rq = lane >> 4, cidx = lane & 15;
    int seg = yb * 4 + wc;
    float c2q[4]; int tq[4];
#pragma unroll
    for (int qi = 0; qi < 4; ++qi) {
        int t = t0base + wc * 64 + qi * 16 + cidx;
        tq[qi] = t;
        c2q[qi] = (t < NT) ? ws[OFF_NORM2C + t] * inv2 : 0.f;
    }
    unsigned long long* keys = (unsigned long long*)(ws + NOFF_MIND);

#pragma unroll
    for (int ri = 0; ri < 4; ++ri) {
#pragma unroll
        for (int reg = 0; reg < 4; ++reg) {
            int row = b0 + wr * 64 + ri * 16 + rq * 4 + reg;
            float x2 = ws[OFF_X2 + row];
            unsigned long long best = ~0ull;
#pragma unroll
            for (int qi = 0; qi < 4; ++qi) {
                float d2 = fmaxf(x2 + c2q[qi] - 2.f * (acc[ri][qi][reg] * inv), 0.f);
                float d2n = __shfl_xor(d2, 1);   // partner t^1 for per-class pair min
                int t = tq[qi];
                if ((t < NT) && ((cidx & 1) == 0))
                    out[(size_t)row * OUTW + (t >> 1)] = -sqrtf(fminf(d2, d2n));
                if (t < NT) {
                    unsigned long long key =
                        ((unsigned long long)__float_as_uint(d2) << 32) | (unsigned)t;
                    best = best < key ? best : key;
                }
            }
#pragma unroll
            for (int off = 1; off < 16; off <<= 1) {
                unsigned long long o = __shfl_xor(best, off);
                best = best < o ? best : o;
            }
            if (cidx == 0) keys[(size_t)row * 32 + seg] = best;
        }
    }
}

// ---------- combine: u64 d^2-keys -> idx, cx (exact recovery), cl2 ----------
__global__ __launch_bounds__(256) void combine32_kernel(float* __restrict__ ws)
{
    int b = blockIdx.x * 256 + threadIdx.x;
    const unsigned long long* keys = (const unsigned long long*)(ws + NOFF_MIND);
    unsigned long long best = keys[(size_t)b * 32];
#pragma unroll
    for (int s = 1; s < 32; ++s) {
        unsigned long long k = keys[(size_t)b * 32 + s];
        best = best < k ? best : k;
    }
    int bt = (int)(best & 0xffffffffull);
    float d2 = __uint_as_float((unsigned)(best >> 32));
    float c2 = ws[OFF_NORM2C + bt] * ws[OFF_SCAL + 2];
    float x2 = ws[OFF_X2 + b];
    ((int*)ws)[OFF_IDX + b] = bt;
    ws[OFF_CX + b] = 0.5f * (x2 + c2 - d2);   // dot = (x2+c2-d^2)/2
    ws[OFF_CL2 + b] = c2;
}

// ===================== 128^2 register-core, 1-plane (for table) =====================
#define LOADA1(buf, ks_) do { _Pragma("unroll") \
    for (int i = 0; i < 4; ++i) { \
        buf[i] = *(const bf16x8*)(aB + (ks_) * 16384 + i * 2048); \
    } } while (0)
#define LOADB1(buf, ks_) do { _Pragma("unroll") \
    for (int i = 0; i < 4; ++i) { \
        buf[i] = *(const bf16x8*)(bB + (ks_) * 16384 + i * 2048); \
    } } while (0)

__device__ __forceinline__ void mfma_core_db1(
    const unsigned char* __restrict__ aP, const unsigned char* __restrict__ bP,
    int lane, int wr, int wc, f32x4 acc[4][4])
{
    const unsigned char* aB = aP + wr * 8192 + lane * 16;
    const unsigned char* bB = bP + wc * 8192 + lane * 16;
    bf16x8 a0[4], a1[4], b0[4], b1[4];
    LOADA1(a0, 0); LOADB1(b0, 0);
    for (int ks = 0; ks < 16; ks += 2) {
        LOADA1(a1, ks + 1); LOADB1(b1, ks + 1);
        PASS4(a0, b0);
        if (ks + 2 < 16) { LOADA1(a0, ks + 2); LOADB1(b0, ks + 2); }
        PASS4(a1, b1);
    }
}

// ---------- invden table (bf16): 1/(||cf[c]-r[t]|| + 1e-9), [c][t] stride 2048 ----------
__global__ __launch_bounds__(256, 2) void table_mfma_kernel(
    const unsigned char* __restrict__ cpack, const unsigned char* __restrict__ rpack,
    ushort* __restrict__ table, const float* __restrict__ ws)
{
    int tid = threadIdx.x, lane = tid & 63, wave = tid >> 6;
    int wr = wave >> 1, wc = wave & 1;
    int c0 = blockIdx.x * 128, t0base = blockIdx.y * 128;
    f32x4 acc[4][4];
#pragma unroll
    for (int i = 0; i < 4; ++i)
#pragma unroll
        for (int q = 0; q < 4; ++q) acc[i][q] = (f32x4){0.f, 0.f, 0.f, 0.f};
    mfma_core_db1(cpack + (size_t)blockIdx.x * 262144, rpack + (size_t)blockIdx.y * 262144,
                  lane, wr, wc, acc);

    float inv  = ws[OFF_SCAL + 1];
    float inv2 = ws[OFF_SCAL + 2];
    int rq = lane >> 4, cidx = lane & 15;
    float r2q[4]; int tq[4];
#pragma unroll
    for (int qi = 0; qi < 4; ++qi) {
        int t = t0base + wc * 64 + qi * 16 + cidx;
        tq[qi] = t;
        r2q[qi] = (t < NT) ? ws[OFF_R2 + t] : 0.f;
    }
#pragma unroll
    for (int ri = 0; ri < 4; ++ri) {
#pragma unroll
        for (int reg = 0; reg < 4; ++reg) {
            int c = c0 + wr * 64 + ri * 16 + rq * 4 + reg;
            if (c < NT) {
                float cl2c = ws[OFF_NORM2C + c] * inv2;
#pragma unroll
                for (int qi = 0; qi < 4; ++qi) {
                    int t = tq[qi];
                    if (t < NT) {
                        float cfr = acc[ri][qi][reg] * inv;
                        float den = sqrtf(fmaxf(cl2c + r2q[qi] - 2.f * cfr, 0.f)) + 1e-9f;
                        table[(size_t)c * 2048 + t] = bf16rn(1.f / den);
                    }
                }
            }
        }
    }
}

// ---------- xr GEMM + rejective min via bf16 table gather (1-plane, BK=64, 16 waves) ----------
__global__ __launch_bounds__(1024) void xr_mfma_kernel(
    const unsigned char* __restrict__ xpack, const unsigned char* __restrict__ rpack,
    const ushort* __restrict__ table, float* __restrict__ ws)
{
    __shared__ unsigned char lds[2 * 65536];
    int tid = threadIdx.x, lane = tid & 63, wave = tid >> 6;
    int wr = wave >> 2, wc = wave & 3;
    int xb = blockIdx.x, yb = blockIdx.y;
    int b0 = xb * 256, t0base = yb * 256;
    f32x4 acc[4][4];
#pragma unroll
    for (int i = 0; i < 4; ++i)
#pragma unroll
        for (int q = 0; q < 4; ++q) acc[i][q] = (f32x4){0.f, 0.f, 0.f, 0.f};
    mfma_core_xr(xpack + (size_t)xb * 524288, rpack + (size_t)yb * 524288,
                 lds, lane, wave, wr, wc, acc);

    int rq = lane >> 4, cidx = lane & 15;
    int seg = yb * 4 + wc;
    float r2q[4]; int tq[4];
#pragma unroll
    for (int qi = 0; qi < 4; ++qi) {
        int t = t0base + wc * 64 + qi * 16 + cidx;
        tq[qi] = t;
        r2q[qi] = (t < NT) ? ws[OFF_R2 + t] : 0.f;
    }
#pragma unroll
    for (int ri = 0; ri < 4; ++ri) {
#pragma unroll
        for (int reg = 0; reg < 4; ++reg) {
            int row = b0 + wr * 64 + ri * 16 + rq * 4 + reg;
            int idx = ((const int*)ws)[OFF_IDX + row];
            float cx  = ws[OFF_CX + row];
            float cl2 = ws[OFF_CL2 + row];
            const ushort* trow = table + (size_t)idx * 2048;
            float tv[4];
#pragma unroll
            for (int qi = 0; qi < 4; ++qi)
                tv[qi] = (tq[qi] < NT)
                    ? __uint_as_float(((uint32_t)trow[tq[qi]]) << 16) : 0.f;
            float mv = INFINITY;
#pragma unroll
            for (int qi = 0; qi < 4; ++qi) {
                if (tq[qi] < NT) {
                    float num = fabsf(cx - acc[ri][qi][reg] - 0.5f * (cl2 - r2q[qi]));
                    mv = fminf(mv, num * tv[qi]);
                }
            }
#pragma unroll
            for (int off = 1; off < 16; off <<= 1) mv = fminf(mv, __shfl_xor(mv, off));
            if (cidx == 0) ws[NOFF_REJP + (size_t)row * 32 + seg] = mv;
        }
    }
}

__global__ __launch_bounds__(256) void rejcombine32_kernel(
    const float* __restrict__ ws, float* __restrict__ out)
{
    int b = blockIdx.x * 256 + threadIdx.x;
    float bd = ws[NOFF_REJP + (size_t)b * 32];
#pragma unroll
    for (int s = 1; s < 32; ++s) bd = fminf(bd, ws[NOFF_REJP + (size_t)b * 32 + s]);
    out[(size_t)b * OUTW + NCLS] = bd;
}

// ===================== fallback path (round-1 f32 VALU pipeline) =====================
#define BK   32
#define LDST 68

__global__ __launch_bounds__(256) void dist_kernel(
    const float* __restrict__ x, const float* __restrict__ cen,
    float* __restrict__ out, float* __restrict__ ws)
{
    __shared__ float Xs[BK][LDST];
    __shared__ float Cs[BK][LDST];
    __shared__ float red_d[64][17];
    __shared__ int   red_t[64][17];
    __shared__ float red_x[64][17];

    int tid = threadIdx.x;
    int tx = tid & 15, ty = tid >> 4;
    int b0 = blockIdx.x * 64;
    int tseg0 = blockIdx.y * 256;
    int tseg1 = min(tseg0 + 256, NT);

    float inv  = ws[OFF_SCAL + 1];
    float inv2 = ws[OFF_SCAL + 2];
    float x2v[4];
#pragma unroll
    for (int i = 0; i < 4; ++i) x2v[i] = ws[OFF_X2 + b0 + ty * 4 + i];

    int lr = tid >> 2;
    int lc = (tid & 3) * 8;

    float mind[4], mdot[4];
    int mint[4];
#pragma unroll
    for (int i = 0; i < 4; ++i) { mind[i] = INFINITY; mint[i] = 0x7fffffff; mdot[i] = 0.f; }

    for (int t0 = tseg0; t0 < tseg1; t0 += 64) {
        float acc[4][4];
#pragma unroll
        for (int i = 0; i < 4; ++i)
#pragma unroll
            for (int jj = 0; jj < 4; ++jj) acc[i][jj] = 0.f;

        for (int k0 = 0; k0 < ND; k0 += BK) {
            {
                const float4 v0 = *(const float4*)&x[(size_t)(b0 + lr) * ND + k0 + lc];
                const float4 v1 = *(const float4*)&x[(size_t)(b0 + lr) * ND + k0 + lc + 4];
                Xs[lc + 0][lr] = v0.x; Xs[lc + 1][lr] = v0.y; Xs[lc + 2][lr] = v0.z; Xs[lc + 3][lr] = v0.w;
                Xs[lc + 4][lr] = v1.x; Xs[lc + 5][lr] = v1.y; Xs[lc + 6][lr] = v1.z; Xs[lc + 7][lr] = v1.w;
            }
            {
                int tr = t0 + lr;
                float4 v0 = make_float4(0.f, 0.f, 0.f, 0.f), v1 = v0;
                if (tr < NT) {
                    v0 = *(const float4*)&cen[(size_t)tr * ND + k0 + lc];
                    v1 = *(const float4*)&cen[(size_t)tr * ND + k0 + lc + 4];
                }
                Cs[lc + 0][lr] = v0.x; Cs[lc + 1][lr] = v0.y; Cs[lc + 2][lr] = v0.z; Cs[lc + 3][lr] = v0.w;
                Cs[lc + 4][lr] = v1.x; Cs[lc + 5][lr] = v1.y; Cs[lc + 6][lr] = v1.z; Cs[lc + 7][lr] = v1.w;
            }
            __syncthreads();
#pragma unroll
            for (int kk = 0; kk < BK; ++kk) {
                float4 av = *(const float4*)&Xs[kk][ty * 4];
                float4 bv = *(const float4*)&Cs[kk][tx * 4];
                float a[4] = {av.x, av.y, av.z, av.w};
                float bb[4] = {bv.x, bv.y, bv.z, bv.w};
#pragma unroll
                for (int i = 0; i < 4; ++i)
#pragma unroll
                    for (int jj = 0; jj < 4; ++jj)
                        acc[i][jj] = fmaf(a[i], bb[jj], acc[i][jj]);
            }
            __syncthreads();
        }

        float distv[4][4];
#pragma unroll
        for (int jj = 0; jj < 4; ++jj) {
            int t = t0 + tx * 4 + jj;
            bool valid = (t < NT);
            float c2 = valid ? ws[OFF_NORM2C + t] * inv2 : 0.f;
#pragma unroll
            for (int i = 0; i < 4; ++i) {
                float dsc = acc[i][jj] * inv;
                float d2 = x2v[i] + c2 - 2.f * dsc;
                float dd = sqrtf(fmaxf(d2, 0.f));
                distv[i][jj] = dd;
                if (valid && (dd < mind[i])) { mind[i] = dd; mint[i] = t; mdot[i] = dsc; }
            }
        }
#pragma unroll
        for (int jp = 0; jp < 2; ++jp) {
            int t = t0 + tx * 4 + jp * 2;
            if (t < NT) {
                int cls = t >> 1;
#pragma unroll
                for (int i = 0; i < 4; ++i) {
                    out[(size_t)(b0 + ty * 4 + i) * OUTW + cls] =
                        -fminf(distv[i][jp * 2], distv[i][jp * 2 + 1]);
                }
            }
        }
    }

#pragma unroll
    for (int i = 0; i < 4; ++i) {
        red_d[ty * 4 + i][tx] = mind[i];
        red_t[ty * 4 + i][tx] = mint[i];
        red_x[ty * 4 + i][tx] = mdot[i];
    }
    __syncthreads();
    if (tid < 64) {
        float bd = red_d[tid][0]; int bt = red_t[tid][0]; float bx = red_x[tid][0];
        for (int q = 1; q < 16; ++q) {
            float d = red_d[tid][q]; int tt = red_t[tid][q];
            if (d < bd || (d == bd && tt < bt)) { bd = d; bt = tt; bx = red_x[tid][q]; }
        }
        int b = b0 + tid;
        int s = blockIdx.y;
        ws[OFF8_MIND + b * 8 + s] = bd;
        ((int*)ws)[OFF8_MINT + b * 8 + s] = bt;
        ws[OFF8_MDOT + b * 8 + s] = bx;
    }
}

__global__ __launch_bounds__(256) void combine_kernel(float* __restrict__ ws)
{
    int b = blockIdx.x * 256 + threadIdx.x;
    float bd = ws[OFF8_MIND + b * 8];
    int   bt = ((int*)ws)[OFF8_MINT + b * 8];
    float bx = ws[OFF8_MDOT + b * 8];
#pragma unroll
    for (int s = 1; s < 8; ++s) {
        float d = ws[OFF8_MIND + b * 8 + s];
        int  tt = ((int*)ws)[OFF8_MINT + b * 8 + s];
        if (d < bd || (d == bd && tt < bt)) { bd = d; bt = tt; bx = ws[OFF8_MDOT + b * 8 + s]; }
    }
    ((int*)ws)[OFF_IDX + b] = bt;
    ws[OFF_CX + b] = bx;
    ws[OFF_CL2 + b] = ws[OFF_NORM2C + bt] * ws[OFF_SCAL + 2];
}

__global__ __launch_bounds__(256) void rej_kernel(
    const float* __restrict__ x, const float* __restrict__ cen,
    const float* __restrict__ rej, float* __restrict__ ws)
{
    __shared__ float Xs[BK][LDST];
    __shared__ float Rs[BK][LDST];
    __shared__ float Ls[BK][LDST];
    __shared__ int idxL[64];
    __shared__ float red_d[64][17];

    int tid = threadIdx.x;
    int tx = tid & 15, ty = tid >> 4;
    int b0 = blockIdx.x * 64;
    int tseg0 = blockIdx.y * 256;
    int tseg1 = min(tseg0 + 256, NT);
    float inv = ws[OFF_SCAL + 1];

    if (tid < 64) idxL[tid] = ((int*)ws)[OFF_IDX + b0 + tid];
    float cxv[4], cl2v[4];
#pragma unroll
    for (int i = 0; i < 4; ++i) {
        cxv[i]  = ws[OFF_CX  + b0 + ty * 4 + i];
        cl2v[i] = ws[OFF_CL2 + b0 + ty * 4 + i];
    }
    __syncthreads();

    int lr = tid >> 2, lc = (tid & 3) * 8;
    int myrow = idxL[lr];

    float minv[4] = {INFINITY, INFINITY, INFINITY, INFINITY};

    for (int t0 = tseg0; t0 < tseg1; t0 += 64) {
        float xr[4][4], cr[4][4];
#pragma unroll
        for (int i = 0; i < 4; ++i)
#pragma unroll
            for (int jj = 0; jj < 4; ++jj) { xr[i][jj] = 0.f; cr[i][jj] = 0.f; }

        for (int k0 = 0; k0 < ND; k0 += BK) {
            {
                const float4 v0 = *(const float4*)&x[(size_t)(b0 + lr) * ND + k0 + lc];
                const float4 v1 = *(const float4*)&x[(size_t)(b0 + lr) * ND + k0 + lc + 4];
                Xs[lc + 0][lr] = v0.x; Xs[lc + 1][lr] = v0.y; Xs[lc + 2][lr] = v0.z; Xs[lc + 3][lr] = v0.w;
                Xs[lc + 4][lr] = v1.x; Xs[lc + 5][lr] = v1.y; Xs[lc + 6][lr] = v1.z; Xs[lc + 7][lr] = v1.w;
            }
            {
                const float4 v0 = *(const float4*)&cen[(size_t)myrow * ND + k0 + lc];
                const float4 v1 = *(const float4*)&cen[(size_t)myrow * ND + k0 + lc + 4];
                Ls[lc + 0][lr] = v0.x * inv; Ls[lc + 1][lr] = v0.y * inv;
                Ls[lc + 2][lr] = v0.z * inv; Ls[lc + 3][lr] = v0.w * inv;
                Ls[lc + 4][lr] = v1.x * inv; Ls[lc + 5][lr] = v1.y * inv;
                Ls[lc + 6][lr] = v1.z * inv; Ls[lc + 7][lr] = v1.w * inv;
            }
            {
                int tr = t0 + lr;
                float4 v0 = make_float4(0.f, 0.f, 0.f, 0.f), v1 = v0;
                if (tr < NT) {
                    v0 = *(const float4*)&rej[(size_t)tr * ND + k0 + lc];
                    v1 = *(const float4*)&rej[(size_t)tr * ND + k0 + lc + 4];
                }
                Rs[lc + 0][lr] = v0.x; Rs[lc + 1][lr] = v0.y; Rs[lc + 2][lr] = v0.z; Rs[lc + 3][lr] = v0.w;
                Rs[lc + 4][lr] = v1.x; Rs[lc + 5][lr] = v1.y; Rs[lc + 6][lr] = v1.z; Rs[lc + 7][lr] = v1.w;
            }
            __syncthreads();
#pragma unroll
            for (int kk = 0; kk < BK; ++kk) {
                float4 av = *(const float4*)&Xs[kk][ty * 4];
                float4 lv = *(const float4*)&Ls[kk][ty * 4];
                float4 rv = *(const float4*)&Rs[kk][tx * 4];
                float a[4] = {av.x, av.y, av.z, av.w};
                float l[4] = {lv.x, lv.y, lv.z, lv.w};
                float r[4] = {rv.x, rv.y, rv.z, rv.w};
#pragma unroll
                for (int i = 0; i < 4; ++i)
#pragma unroll
                    for (int jj = 0; jj < 4; ++jj) {
                        xr[i][jj] = fmaf(a[i], r[jj], xr[i][jj]);
                        cr[i][jj] = fmaf(l[i], r[jj], cr[i][jj]);
                    }
            }
            __syncthreads();
        }

#pragma unroll
        for (int jj = 0; jj < 4; ++jj) {
            int t = t0 + tx * 4 + jj;
            if (t < NT) {
                float r2 = ws[OFF_R2 + t];
#pragma unroll
                for (int i = 0; i < 4; ++i) {
                    float num = fabsf(cxv[i] - xr[i][jj] - 0.5f * (cl2v[i] - r2));
                    float den = sqrtf(fmaxf(cl2v[i] + r2 - 2.f * cr[i][jj], 0.f)) + 1e-9f;
                    minv[i] = fminf(minv[i], num / den);
                }
            }
        }
    }

#pragma unroll
    for (int i = 0; i < 4; ++i) red_d[ty * 4 + i][tx] = minv[i];
    __syncthreads();
    if (tid < 64) {
        float bd = red_d[tid][0];
        for (int q = 1; q < 16; ++q) bd = fminf(bd, red_d[tid][q]);
        ws[OFF8_REJP + (size_t)(b0 + tid) * 8 + blockIdx.y] = bd;
    }
}

__global__ __launch_bounds__(256) void rejcombine_kernel(
    const float* __restrict__ ws, float* __restrict__ out)
{
    int b = blockIdx.x * 256 + threadIdx.x;
    float bd = ws[OFF8_REJP + b * 8];
#pragma unroll
    for (int s = 1; s < 8; ++s) bd = fminf(bd, ws[OFF8_REJP + b * 8 + s]);
    out[(size_t)b * OUTW + NCLS] = bd;
}

// ===================== launch =====================
extern "C" void kernel_launch(void* const* d_in, const int* in_sizes, int n_in,
                              void* d_out, int out_size, void* d_ws, size_t ws_size,
                              hipStream_t stream)
{
    const float* x   = (const float*)d_in[0];
    const float* cen = (const float*)d_in[1];
    const float* rej = (const float*)d_in[2];
    float* out = (float*)d_out;
    float* ws  = (float*)d_ws;
    unsigned char* wsb = (unsigned char*)d_ws;

    rownorm_kernel<<<2 * NT + NB, 64, 0, stream>>>(cen, rej, x, ws);
    maxnorm_kernel<<<1, 256, 0, stream>>>(ws);

    if (ws_size >= WS_NEED) {
        // fast path (best measured config, r14 = 153.1 us): dist r11-golden 3-plane
        // 256^2 16-wave; xr BK=64 1-plane per-substep loads; bf16 invden table
        pack_kernel<<<2048, 256, 0, stream>>>(x,   wsb + PACKX_B, NB);
        pack_kernel<<<512,  256, 0, stream>>>(cen, wsb + PACKC_B, NT);
        pack_kernel<<<512,  256, 0, stream>>>(rej, wsb + PACKR_B, NT);
        dist_mfma_kernel<<<dim3(32, 8), 1024, 0, stream>>>(wsb + PACKX_B, wsb + PACKC_B, out, ws);
        combine32_kernel<<<32, 256, 0, stream>>>(ws);
        table_mfma_kernel<<<dim3(16, 16), 256, 0, stream>>>(wsb + PACKC_B, wsb + PACKR_B,
                                                            (ushort*)(wsb + PACKT_B), ws);
        xr_mfma_kernel<<<dim3(32, 8), 1024, 0, stream>>>(wsb + PACKX_B, wsb + PACKR_B,
                                                         (const ushort*)(wsb + PACKT_B), ws);
        rejcombine32_kernel<<<32, 256, 0, stream>>>(ws, out);
    } else {
        // fallback: round-1 f32 VALU pipeline
        dist_kernel<<<dim3(NB / 64, 8), 256, 0, stream>>>(x, cen, out, ws);
        combine_kernel<<<NB / 256, 256, 0, stream>>>(ws);
        rej_kernel<<<dim3(NB / 64, 8), 256, 0, stream>>>(x, cen, rej, ws);
        rejcombine_kernel<<<NB / 256, 256, 0, stream>>>(ws, out);
    }
}